// Round 1
// 1609.278 us; speedup vs baseline: 2.3027x; 2.3027x over previous
//
#include <hip/hip_runtime.h>

#define T_TOK 4096
#define DDIM 2048
#define FDIM 4096
#define NEXP 8
#define ALPHA_C 1.702f
#define FLIMIT 7.0f
#define BM 128
#define BN 128
#define BK 32

typedef __attribute__((ext_vector_type(8))) short s16x8;   // 8 bf16 (4 VGPRs)
typedef __attribute__((ext_vector_type(4))) float f32x4;

// fp32 -> bf16 bits, round-to-nearest-even (inputs are finite; no NaN path)
__device__ __forceinline__ short f2bf(float f) {
  unsigned int u = __float_as_uint(f);
  u += 0x7fffu + ((u >> 16) & 1u);
  return (short)(unsigned short)(u >> 16);
}

// async global->LDS, 16B per lane; LDS dest must be lane-linear per wave
#define GL2LDS(g, l)                                            \
  __builtin_amdgcn_global_load_lds(                             \
      (__attribute__((address_space(1))) void*)(void*)(g),      \
      (__attribute__((address_space(3))) void*)(l), 16, 0, 0)

// ---------------- router: logits, top-2, expert lists, x -> bf16 ----------------
__global__ __launch_bounds__(256) void router_kernel(
    const float* __restrict__ x, const float* __restrict__ rw,
    const float* __restrict__ rb, short* __restrict__ xb,
    int* __restrict__ counts, int* __restrict__ toklist,
    float* __restrict__ wlist) {
  const int t = (int)((blockIdx.x * 256 + threadIdx.x) >> 6);  // one wave per token
  const int lane = threadIdx.x & 63;
  const float* xr = x + (size_t)t * DDIM;
  float acc[NEXP];
#pragma unroll
  for (int e = 0; e < NEXP; ++e) acc[e] = 0.f;
  for (int j = 0; j < DDIM / 64; ++j) {
    const int idx = j * 64 + lane;
    const float xv = xr[idx];
    xb[(size_t)t * DDIM + idx] = f2bf(xv);
#pragma unroll
    for (int e = 0; e < NEXP; ++e) acc[e] += xv * rw[e * DDIM + idx];
  }
#pragma unroll
  for (int e = 0; e < NEXP; ++e) {
#pragma unroll
    for (int off = 32; off > 0; off >>= 1) acc[e] += __shfl_down(acc[e], off, 64);
  }
  if (lane == 0) {
    float l0 = -1e30f;
    int e0 = 0;
#pragma unroll
    for (int e = 0; e < NEXP; ++e) {
      acc[e] += rb[e];
      if (acc[e] > l0) { l0 = acc[e]; e0 = e; }
    }
    float l1 = -1e30f;
    int e1 = 0;
#pragma unroll
    for (int e = 0; e < NEXP; ++e) {
      if (e != e0 && acc[e] > l1) { l1 = acc[e]; e1 = e; }
    }
    const float wA = 1.f / (1.f + __expf(l1 - l0));
    const float wB = 1.f - wA;
    const int s0 = atomicAdd(&counts[e0], 1);
    toklist[e0 * T_TOK + s0] = t * 2;
    wlist[e0 * T_TOK + s0] = wA;
    const int s1 = atomicAdd(&counts[e1], 1);
    toklist[e1 * T_TOK + s1] = t * 2 + 1;
    wlist[e1 * T_TOK + s1] = wB;
  }
}

// ---------------- transpose+convert: in [R][C] fp32 -> out [C][R] bf16, z = expert ----------------
__global__ __launch_bounds__(256) void transpose_bf16_kernel(
    const float* __restrict__ in, short* __restrict__ out, int R, int C) {
  __shared__ __align__(16) float L[64][68];  // pad 68: 16B-aligned rows, conflict-free col reads
  const int tid = threadIdx.x;
  const size_t base = (size_t)blockIdx.z * R * C;
  const int c0 = blockIdx.x * 64, r0 = blockIdx.y * 64;
  const int li = tid >> 4, lj = (tid & 15) * 4;
  const float* src = in + base + (size_t)(r0 + li) * C + (c0 + lj);
#pragma unroll
  for (int p = 0; p < 4; ++p) {
    const float4 v = *(const float4*)(src + (size_t)p * 16 * C);
    *(float4*)&L[li + p * 16][lj] = v;
  }
  __syncthreads();
  const int oc = tid >> 2, ok = (tid & 3) * 16;
  s16x8 lo, hi;
#pragma unroll
  for (int s = 0; s < 8; ++s) lo[s] = f2bf(L[ok + s][oc]);
#pragma unroll
  for (int s = 0; s < 8; ++s) hi[s] = f2bf(L[ok + 8 + s][oc]);
  short* dp = out + base + (size_t)(c0 + oc) * R + (r0 + ok);
  *(s16x8*)dp = lo;
  *(s16x8*)(dp + 8) = hi;
}

// ---------------- GEMM1: h = swiglu(Xg@w1+b1, Xg@w3+b3), gathered rows ----------------
// w1t/w3t: bf16 [E][F][D] (K-contiguous). All staging via global_load_lds.
__global__ __launch_bounds__(256, 2) void gemm1_kernel(
    const short* __restrict__ xb, const short* __restrict__ w1t,
    const float* __restrict__ b1g, const short* __restrict__ w3t,
    const float* __restrict__ b3g, const int* __restrict__ counts,
    const int* __restrict__ toklist, short* __restrict__ h) {
  // XCD-chunked swizzle: each chunk of 32 consecutive work-ids (one (n,e) m-strip)
  // lands on one XCD so the 8 active m-blocks share the weight panel in its L2.
  const int flat = blockIdx.x + 32 * (blockIdx.y + 32 * blockIdx.z);
  const int xcd = flat & 7;
  const int slot = flat >> 3;
  const int work = ((((slot >> 5) << 3) + xcd) << 5) + (slot & 31);
  const int e = work >> 10;
  const int n0 = ((work >> 5) & 31) * BN;
  const int m0 = (work & 31) * BM;
  const int n_e = counts[e];
  if (m0 >= n_e) return;
  const short* w1 = w1t + (size_t)e * FDIM * DDIM;
  const short* w3 = w3t + (size_t)e * FDIM * DDIM;

  __shared__ __align__(16) short Alds[BM * BK];
  __shared__ __align__(16) short B1lds[BN * BK];  // [n][k]
  __shared__ __align__(16) short B3lds[BN * BK];
  __shared__ int rowtok[BM];

  const int tid = threadIdx.x;
  if (tid < BM) {
    int r = m0 + tid;
    if (r >= n_e) r = n_e - 1;  // clamp; stores masked in epilogue
    rowtok[tid] = toklist[e * T_TOK + r];
  }
  __syncthreads();

  // lane-linear staging map: tid -> row tid/4, k-chunk (tid&3)*8 shorts (16B)
  const int arow = tid >> 2;
  const int achk = (tid & 3) * 8;
  const short* asrc0 = xb + (size_t)(rowtok[arow] >> 1) * DDIM + achk;
  const short* asrc1 = xb + (size_t)(rowtok[arow + 64] >> 1) * DDIM + achk;
  const short* b1src0 = w1 + (size_t)(n0 + arow) * DDIM + achk;
  const short* b1src1 = w1 + (size_t)(n0 + arow + 64) * DDIM + achk;
  const short* b3src0 = w3 + (size_t)(n0 + arow) * DDIM + achk;
  const short* b3src1 = w3 + (size_t)(n0 + arow + 64) * DDIM + achk;

  const int wave = tid >> 6;
  const int lane = tid & 63;
  const int wm = (wave >> 1) * 64;
  const int wn = (wave & 1) * 64;
  const int lr = lane & 15;
  const int lq = lane >> 4;

  f32x4 accg[4][4], accu[4][4];
  const f32x4 zero = {0.f, 0.f, 0.f, 0.f};
#pragma unroll
  for (int i = 0; i < 4; ++i)
#pragma unroll
    for (int j = 0; j < 4; ++j) { accg[i][j] = zero; accu[i][j] = zero; }

  for (int kt = 0; kt < DDIM / BK; ++kt) {
    __syncthreads();  // all waves done reading LDS from prev iter
    const int ko = kt * BK;
    GL2LDS(asrc0 + ko, &Alds[tid * 8]);
    GL2LDS(asrc1 + ko, &Alds[2048 + tid * 8]);
    GL2LDS(b1src0 + ko, &B1lds[tid * 8]);
    GL2LDS(b1src1 + ko, &B1lds[2048 + tid * 8]);
    GL2LDS(b3src0 + ko, &B3lds[tid * 8]);
    GL2LDS(b3src1 + ko, &B3lds[2048 + tid * 8]);
    __syncthreads();  // drains vmcnt -> LDS tiles ready
    s16x8 af[4];
#pragma unroll
    for (int mf = 0; mf < 4; ++mf)
      af[mf] = *(const s16x8*)&Alds[(wm + mf * 16 + lr) * BK + lq * 8];
#pragma unroll
    for (int nf = 0; nf < 4; ++nf) {
      s16x8 bg = *(const s16x8*)&B1lds[(wn + nf * 16 + lr) * BK + lq * 8];
      s16x8 bu = *(const s16x8*)&B3lds[(wn + nf * 16 + lr) * BK + lq * 8];
#pragma unroll
      for (int mf = 0; mf < 4; ++mf) {
        accg[mf][nf] = __builtin_amdgcn_mfma_f32_16x16x32_bf16(af[mf], bg, accg[mf][nf], 0, 0, 0);
        accu[mf][nf] = __builtin_amdgcn_mfma_f32_16x16x32_bf16(af[mf], bu, accu[mf][nf], 0, 0, 0);
      }
    }
  }

  // epilogue: bias + oai-swiglu, store h (bf16)
#pragma unroll
  for (int nf = 0; nf < 4; ++nf) {
    const int col = n0 + wn + nf * 16 + lr;
    const float bg = b1g[e * FDIM + col];
    const float bu = b3g[e * FDIM + col];
#pragma unroll
    for (int mf = 0; mf < 4; ++mf) {
#pragma unroll
      for (int r = 0; r < 4; ++r) {
        const int row = wm + mf * 16 + lq * 4 + r;
        if (m0 + row < n_e) {
          float gate = accg[mf][nf][r] + bg;
          float up = accu[mf][nf][r] + bu;
          gate = fminf(gate, FLIMIT);
          up = fminf(fmaxf(up, -FLIMIT), FLIMIT);
          const float glu = gate / (1.f + __expf(-ALPHA_C * gate));
          const float hv = (up + 1.f) * glu;
          h[(size_t)rowtok[row] * FDIM + col] = f2bf(hv);
        }
      }
    }
  }
}

// ---------------- GEMM2: out += w_slot * (Hg@w2 + b2), scatter via atomicAdd ----------------
// w2t: bf16 [E][D][F] (K-contiguous).
__global__ __launch_bounds__(256, 3) void gemm2_kernel(
    const short* __restrict__ h, const short* __restrict__ w2t,
    const float* __restrict__ b2g, const int* __restrict__ counts,
    const int* __restrict__ toklist, const float* __restrict__ wlist,
    float* __restrict__ out) {
  const int flat = blockIdx.x + 32 * (blockIdx.y + 16 * blockIdx.z);
  const int xcd = flat & 7;
  const int slot = flat >> 3;
  const int work = ((((slot >> 5) << 3) + xcd) << 5) + (slot & 31);
  const int e = work >> 9;
  const int n0 = ((work >> 5) & 15) * BN;  // D columns
  const int m0 = (work & 31) * BM;
  const int n_e = counts[e];
  if (m0 >= n_e) return;
  const short* w2 = w2t + (size_t)e * DDIM * FDIM;

  __shared__ __align__(16) short Alds[BM * BK];
  __shared__ __align__(16) short Blds[BN * BK];  // [n][k]
  __shared__ int rowtok[BM];
  __shared__ float roww[BM];

  const int tid = threadIdx.x;
  if (tid < BM) {
    int r = m0 + tid;
    if (r >= n_e) r = n_e - 1;
    rowtok[tid] = toklist[e * T_TOK + r];
    roww[tid] = wlist[e * T_TOK + r];
  }
  __syncthreads();

  const int arow = tid >> 2;
  const int achk = (tid & 3) * 8;
  const short* asrc0 = h + (size_t)rowtok[arow] * FDIM + achk;
  const short* asrc1 = h + (size_t)rowtok[arow + 64] * FDIM + achk;
  const short* bsrc0 = w2 + (size_t)(n0 + arow) * FDIM + achk;
  const short* bsrc1 = w2 + (size_t)(n0 + arow + 64) * FDIM + achk;

  const int wave = tid >> 6;
  const int lane = tid & 63;
  const int wm = (wave >> 1) * 64;
  const int wn = (wave & 1) * 64;
  const int lr = lane & 15;
  const int lq = lane >> 4;

  f32x4 acc[4][4];
  const f32x4 zero = {0.f, 0.f, 0.f, 0.f};
#pragma unroll
  for (int i = 0; i < 4; ++i)
#pragma unroll
    for (int j = 0; j < 4; ++j) acc[i][j] = zero;

  for (int kt = 0; kt < FDIM / BK; ++kt) {
    __syncthreads();
    const int ko = kt * BK;
    GL2LDS(asrc0 + ko, &Alds[tid * 8]);
    GL2LDS(asrc1 + ko, &Alds[2048 + tid * 8]);
    GL2LDS(bsrc0 + ko, &Blds[tid * 8]);
    GL2LDS(bsrc1 + ko, &Blds[2048 + tid * 8]);
    __syncthreads();
    s16x8 af[4];
#pragma unroll
    for (int mf = 0; mf < 4; ++mf)
      af[mf] = *(const s16x8*)&Alds[(wm + mf * 16 + lr) * BK + lq * 8];
#pragma unroll
    for (int nf = 0; nf < 4; ++nf) {
      s16x8 bf = *(const s16x8*)&Blds[(wn + nf * 16 + lr) * BK + lq * 8];
#pragma unroll
      for (int mf = 0; mf < 4; ++mf)
        acc[mf][nf] = __builtin_amdgcn_mfma_f32_16x16x32_bf16(af[mf], bf, acc[mf][nf], 0, 0, 0);
    }
  }

#pragma unroll
  for (int nf = 0; nf < 4; ++nf) {
    const int col = n0 + wn + nf * 16 + lr;
    const float b2v = b2g[e * DDIM + col];
#pragma unroll
    for (int mf = 0; mf < 4; ++mf) {
#pragma unroll
      for (int r = 0; r < 4; ++r) {
        const int row = wm + mf * 16 + lq * 4 + r;
        if (m0 + row < n_e) {
          const float y = acc[mf][nf][r] + b2v;
          atomicAdd(&out[(size_t)(rowtok[row] >> 1) * DDIM + col], roww[row] * y);
        }
      }
    }
  }
}

extern "C" void kernel_launch(void* const* d_in, const int* in_sizes, int n_in,
                              void* d_out, int out_size, void* d_ws, size_t ws_size,
                              hipStream_t stream) {
  const float* x  = (const float*)d_in[0];
  const float* rw = (const float*)d_in[1];
  const float* rb = (const float*)d_in[2];
  const float* w1 = (const float*)d_in[3];
  const float* b1 = (const float*)d_in[4];
  const float* w3 = (const float*)d_in[5];
  const float* b3 = (const float*)d_in[6];
  const float* w2 = (const float*)d_in[7];
  const float* b2 = (const float*)d_in[8];
  float* out = (float*)d_out;

  char* ws = (char*)d_ws;
  int* counts = (int*)ws;                                    // 32 B
  int* toklist = (int*)(ws + 1024);                          // 128 KB
  float* wlist = (float*)(ws + 1024 + (size_t)NEXP * T_TOK * 4);
  short* xb  = (short*)(ws + (1 << 20));                     // 16 MB @ 1 MB
  short* h   = (short*)(ws + (1 << 20) + (size_t)T_TOK * DDIM * 2);  // 64 MB @ 17 MB
  short* w1t = (short*)(ws + (96ull << 20));                 // 128 MB: bf16 [E][F][D]
  short* w3t = (short*)(ws + (224ull << 20));                // 128 MB: bf16 [E][F][D]
  short* w2t = (short*)(ws + (352ull << 20));                // 128 MB: bf16 [E][D][F]

  hipMemsetAsync(counts, 0, NEXP * sizeof(int), stream);
  hipMemsetAsync(out, 0, (size_t)out_size * sizeof(float), stream);

  router_kernel<<<dim3(T_TOK / 4), dim3(256), 0, stream>>>(x, rw, rb, xb, counts,
                                                           toklist, wlist);
  transpose_bf16_kernel<<<dim3(FDIM / 64, DDIM / 64, NEXP), dim3(256), 0, stream>>>(
      w1, w1t, DDIM, FDIM);
  transpose_bf16_kernel<<<dim3(FDIM / 64, DDIM / 64, NEXP), dim3(256), 0, stream>>>(
      w3, w3t, DDIM, FDIM);
  transpose_bf16_kernel<<<dim3(DDIM / 64, FDIM / 64, NEXP), dim3(256), 0, stream>>>(
      w2, w2t, FDIM, DDIM);
  gemm1_kernel<<<dim3(32, 32, 8), dim3(256), 0, stream>>>(xb, w1t, b1, w3t, b3,
                                                          counts, toklist, h);
  gemm2_kernel<<<dim3(32, 16, 8), dim3(256), 0, stream>>>(h, w2t, b2, counts,
                                                          toklist, wlist, out);
}